// Round 2
// baseline (350.896 us; speedup 1.0000x reference)
//
#include <hip/hip_runtime.h>
#include <math.h>

#define B_ 32
#define S_ 1024
#define H_ 512
#define K_ 1024                 // 2*H
#define M_ (B_ * S_)            // 32768

typedef __attribute__((ext_vector_type(8))) short bf16x8;
typedef __attribute__((ext_vector_type(16))) float f32x16;

// Round-half-up split: f = hi + lo.  Residual r = f - fh is EXACT regardless
// of hi's rounding mode, so half-up matches RNE accuracy (total error =
// lo rounding <= 2^-18 rel).
__device__ __forceinline__ void split_bf16(float f, unsigned short& hi, unsigned short& lo) {
    unsigned u = __float_as_uint(f);
    unsigned r = u + 0x8000u;
    hi = (unsigned short)(r >> 16);
    float fh = __uint_as_float(r & 0xffff0000u);
    float res = f - fh;
    lo = (unsigned short)((__float_as_uint(res) + 0x8000u) >> 16);
}

// split 8 fp32 -> two bf16x8 fragments (hi, lo); v_perm packs 2 halves/op.
__device__ __forceinline__ void split8_frag(const float4& x, const float4& y,
                                            bf16x8& hi, bf16x8& lo) {
    float f[8] = {x.x, x.y, x.z, x.w, y.x, y.y, y.z, y.w};
    unsigned hr[8], lr[8];
    #pragma unroll
    for (int i = 0; i < 8; ++i) {
        unsigned u = __float_as_uint(f[i]);
        unsigned r = u + 0x8000u;
        hr[i] = r;
        float fh = __uint_as_float(r & 0xffff0000u);
        lr[i] = __float_as_uint(f[i] - fh) + 0x8000u;
    }
    union { uint4 u; bf16x8 v; } H, L;
    H.u.x = __builtin_amdgcn_perm(hr[1], hr[0], 0x07060302u);
    H.u.y = __builtin_amdgcn_perm(hr[3], hr[2], 0x07060302u);
    H.u.z = __builtin_amdgcn_perm(hr[5], hr[4], 0x07060302u);
    H.u.w = __builtin_amdgcn_perm(hr[7], hr[6], 0x07060302u);
    L.u.x = __builtin_amdgcn_perm(lr[1], lr[0], 0x07060302u);
    L.u.y = __builtin_amdgcn_perm(lr[3], lr[2], 0x07060302u);
    L.u.z = __builtin_amdgcn_perm(lr[5], lr[4], 0x07060302u);
    L.u.w = __builtin_amdgcn_perm(lr[7], lr[6], 0x07060302u);
    hi = H.v;
    lo = L.v;
}

// tanh via HW exp + rcp: (e^2x - 1)/(e^2x + 1).  ~8 ops, |err| ~1e-6.
__device__ __forceinline__ float fast_tanh(float x) {
    float xc = fminf(fmaxf(x, -15.f), 15.f);
    float t = __expf(2.0f * xc);
    return (t - 1.0f) * __builtin_amdgcn_rcpf(t + 1.0f);
}

// ---------------------------------------------------------------------------
// Kernel 1: merged prep.
//   blocks [0,256):  hb[b][h] = sum_k hidden[b][k]*W[k][h] + bias[h]
//   blocks [256,768): transpose + bf16-split We (K x 512) into FRAGMENT-TILED
//     layout: short index s = ((c*64 + t)*64 + lane)*8 + j  where
//     c = n>>5, t = k>>4, lane = ((k>>3)&1)*32 + (n&31), j = k&7.
//     A wave's B-fragment (32 cols x 16 k) is then ONE coalesced 1KB load.
// ---------------------------------------------------------------------------
__global__ __launch_bounds__(256) void prep_kernel(
    const float* __restrict__ hidden, const float* __restrict__ W,
    const float* __restrict__ bias, float* __restrict__ hb,
    unsigned short* __restrict__ Wh, unsigned short* __restrict__ Wl)
{
    __shared__ float red[4][64];
    __shared__ float t[32][33];
    const int bx = blockIdx.x;
    if (bx < 256) {
        const int tid = threadIdx.x;
        const int h0  = (bx & 7) * 64;
        const int b   = bx >> 3;
        const int h   = h0 + (tid & 63);
        const int ks  = tid >> 6;              // 4 k-slices of 128
        const float* hrow = hidden + b * H_;
        float acc = 0.f;
        #pragma unroll 8
        for (int k = ks * 128; k < ks * 128 + 128; ++k)
            acc = fmaf(hrow[k], W[(size_t)k * H_ + h], acc);
        red[ks][tid & 63] = acc;
        __syncthreads();
        if (tid < 64)
            hb[b * H_ + h0 + tid] = red[0][tid] + red[1][tid] + red[2][tid]
                                  + red[3][tid] + bias[h0 + tid];
    } else {
        const float* We = W + (size_t)H_ * H_;   // rows [H, 3H)
        const int cx = bx - 256;                  // 0..511
        const int k0 = (cx & 31) * 32, n0 = (cx >> 5) * 32;
        const int tx = threadIdx.x & 31, ty = threadIdx.x >> 5;   // ty 0..7
        #pragma unroll
        for (int j = 0; j < 4; ++j) {
            const int k = ty + 8 * j;
            t[k][tx] = We[(size_t)(k0 + k) * H_ + n0 + tx];
        }
        __syncthreads();
        #pragma unroll
        for (int j = 0; j < 4; ++j) {
            const int n    = ty + 8 * j;
            const int ncol = n0 + n;
            const int k    = k0 + tx;
            unsigned short hi, lo;
            split_bf16(t[tx][n], hi, lo);
            const int c     = ncol >> 5;
            const int tt    = k >> 4;
            const int lane_ = ((k >> 3) & 1) * 32 + (ncol & 31);
            const size_t s  = ((size_t)(c * 64 + tt) * 64 + lane_) * 8 + (k & 7);
            Wh[s] = hi;
            Wl[s] = lo;
        }
    }
}

// ---------------------------------------------------------------------------
// Kernel 2: LDS-free streaming MFMA GEMM.
//   No __shared__ staging, no barriers in the K-loop.  Per wave (64x64 tile):
//   A fp32 -> regs (lane pairs read adjacent 32B -> full-line coalescing),
//   split to bf16 hi/lo in-reg; B read as pre-tiled 1KB coalesced fragments
//   (L2-resident, 2MB).  Depth-1 register prefetch: B(i+1) issued at step
//   start, A(i+1) after the split -> compiler-counted vmcnt pipeline, ~775cy
//   of MFMA to hide L2 latency.  XCD-bijective swizzle kept for L2 locality.
// ---------------------------------------------------------------------------
__global__ __launch_bounds__(256, 2) void gemm_fused(
    const float* __restrict__ EO,             // (M, K) fp32
    const unsigned short* __restrict__ Bth,   // tiled (16,64,64,8) bf16 hi
    const unsigned short* __restrict__ Btl,   // tiled (16,64,64,8) bf16 lo
    const float* __restrict__ hb, const float* __restrict__ v,
    float* __restrict__ partial)              // (4, M)
{
    __shared__ float red[256];

    const int tid  = threadIdx.x;
    // XCD-aware decode: bid%8 = XCD; within an XCD, nt fastest then mt.
    const int bid  = blockIdx.x;
    const int jb   = bid >> 3;
    const int mt   = (bid & 7) * 32 + (jb >> 2);  // 0..255
    const int nt   = jb & 3;                       // 0..3
    const int row0 = mt * 128;
    const int col0 = nt * 128;
    const int batch = row0 >> 10;

    const int lane   = tid & 63;
    const int wave   = tid >> 6;
    const int wm     = wave >> 1, wn = wave & 1;
    const int lane32 = lane & 31, khalf = lane >> 5;

    // A row bases: lane holds A[row][k], row = base + lane32, k = khalf*8 + j
    const float* aP[2];
    #pragma unroll
    for (int fi = 0; fi < 2; ++fi)
        aP[fi] = EO + (size_t)(row0 + wm * 64 + fi * 32 + lane32) * K_ + khalf * 8;

    // B fragment bases: frag (c, t) at shorts ((c*64+t)*64 + lane)*8
    const unsigned short* bPh[2];
    const unsigned short* bPl[2];
    #pragma unroll
    for (int fj = 0; fj < 2; ++fj) {
        const int c = nt * 4 + wn * 2 + fj;
        bPh[fj] = Bth + (size_t)(c * 64) * 512 + lane * 8;
        bPl[fj] = Btl + (size_t)(c * 64) * 512 + lane * 8;
    }

    f32x16 acc[2][2];
    #pragma unroll
    for (int fi = 0; fi < 2; ++fi)
        #pragma unroll
        for (int fj = 0; fj < 2; ++fj)
            #pragma unroll
            for (int e = 0; e < 16; ++e)
                acc[fi][fj][e] = 0.f;

    // ---- prologue: load A(0), B(0) ----
    float4 Afp[2][2][2];                      // [fi][ks][half] fp32 prefetch
    bf16x8 Bh0[2][2], Bl0[2][2], Bh1[2][2], Bl1[2][2];
    #pragma unroll
    for (int fi = 0; fi < 2; ++fi)
        #pragma unroll
        for (int ks = 0; ks < 2; ++ks) {
            Afp[fi][ks][0] = *reinterpret_cast<const float4*>(aP[fi] + ks * 16);
            Afp[fi][ks][1] = *reinterpret_cast<const float4*>(aP[fi] + ks * 16 + 4);
        }
    #pragma unroll
    for (int fj = 0; fj < 2; ++fj)
        #pragma unroll
        for (int ks = 0; ks < 2; ++ks) {
            Bh0[fj][ks] = *reinterpret_cast<const bf16x8*>(bPh[fj] + ks * 512);
            Bl0[fj][ks] = *reinterpret_cast<const bf16x8*>(bPl[fj] + ks * 512);
        }

// One K-step (BK=32): prefetch B(i+1) -> split A(i) -> prefetch A(i+1) -> 24 MFMA
#define STEP(BHc, BLc, BHn, BLn, I, PF)                                        \
  {                                                                            \
    if (PF) {                                                                  \
      _Pragma("unroll") for (int fj = 0; fj < 2; ++fj)                         \
        _Pragma("unroll") for (int ks = 0; ks < 2; ++ks) {                     \
          BHn[fj][ks] = *reinterpret_cast<const bf16x8*>(                      \
              bPh[fj] + ((I) + 1) * 1024 + ks * 512);                          \
          BLn[fj][ks] = *reinterpret_cast<const bf16x8*>(                      \
              bPl[fj] + ((I) + 1) * 1024 + ks * 512);                          \
        }                                                                      \
    }                                                                          \
    bf16x8 ah[2][2], al[2][2];                                                 \
    _Pragma("unroll") for (int fi = 0; fi < 2; ++fi)                           \
      _Pragma("unroll") for (int ks = 0; ks < 2; ++ks)                         \
        split8_frag(Afp[fi][ks][0], Afp[fi][ks][1], ah[fi][ks], al[fi][ks]);   \
    if (PF) {                                                                  \
      _Pragma("unroll") for (int fi = 0; fi < 2; ++fi)                         \
        _Pragma("unroll") for (int ks = 0; ks < 2; ++ks) {                     \
          Afp[fi][ks][0] = *reinterpret_cast<const float4*>(                   \
              aP[fi] + ((I) + 1) * 32 + ks * 16);                              \
          Afp[fi][ks][1] = *reinterpret_cast<const float4*>(                   \
              aP[fi] + ((I) + 1) * 32 + ks * 16 + 4);                          \
        }                                                                      \
    }                                                                          \
    _Pragma("unroll") for (int fi = 0; fi < 2; ++fi)                           \
      _Pragma("unroll") for (int fj = 0; fj < 2; ++fj)                         \
        _Pragma("unroll") for (int ks = 0; ks < 2; ++ks) {                     \
          acc[fi][fj] = __builtin_amdgcn_mfma_f32_32x32x16_bf16(               \
              ah[fi][ks], BHc[fj][ks], acc[fi][fj], 0, 0, 0);                  \
          acc[fi][fj] = __builtin_amdgcn_mfma_f32_32x32x16_bf16(               \
              ah[fi][ks], BLc[fj][ks], acc[fi][fj], 0, 0, 0);                  \
          acc[fi][fj] = __builtin_amdgcn_mfma_f32_32x32x16_bf16(               \
              al[fi][ks], BHc[fj][ks], acc[fi][fj], 0, 0, 0);                  \
        }                                                                      \
  }

    for (int it = 0; it < 15; ++it) {
        STEP(Bh0, Bl0, Bh1, Bl1, 2 * it,     1);
        STEP(Bh1, Bl1, Bh0, Bl0, 2 * it + 1, 1);
    }
    STEP(Bh0, Bl0, Bh1, Bl1, 30, 1);
    STEP(Bh1, Bl1, Bh0, Bl0, 31, 0);
#undef STEP

    // ---- epilogue: tanh(acc + hb)*v, reduce over this block's 128 cols ----
    // 32x32 C layout: col = lane&31, row = (reg&3) + 8*(reg>>2) + 4*(lane>>5).
    const float* hb_row = hb + batch * H_;
    float hbv[2], vv[2];
    #pragma unroll
    for (int fj = 0; fj < 2; ++fj) {
        const int c = col0 + wn * 64 + fj * 32 + lane32;
        hbv[fj] = hb_row[c];
        vv[fj]  = v[c];
    }
    #pragma unroll
    for (int fi = 0; fi < 2; ++fi)
        #pragma unroll
        for (int r = 0; r < 16; ++r) {
            float rs = 0.f;
            #pragma unroll
            for (int fj = 0; fj < 2; ++fj)
                rs = fmaf(fast_tanh(acc[fi][fj][r] + hbv[fj]), vv[fj], rs);
            rs += __shfl_xor(rs, 1, 64);
            rs += __shfl_xor(rs, 2, 64);
            rs += __shfl_xor(rs, 4, 64);
            rs += __shfl_xor(rs, 8, 64);
            rs += __shfl_xor(rs, 16, 64);
            if (lane32 == 0) {
                const int row = wm * 64 + fi * 32 + (r & 3) + 8 * (r >> 2) + 4 * khalf;
                red[row * 2 + wn] = rs;
            }
        }
    __syncthreads();
    if (tid < 128)
        partial[(size_t)nt * M_ + row0 + tid] = red[tid * 2] + red[tid * 2 + 1];
}

// ---------------------------------------------------------------------------
// Kernel 3: per-batch softmax over S=1024 (sum of 4 partials)
// ---------------------------------------------------------------------------
__global__ __launch_bounds__(256) void softmax_kernel(
    const float* __restrict__ partial, float* __restrict__ out)
{
    const int b = blockIdx.x;
    const int tid = threadIdx.x;
    float val[4];
    float lmax = -3.0e38f;
    #pragma unroll
    for (int q = 0; q < 4; ++q) {
        const int idx = b * S_ + tid + 256 * q;
        float sum = partial[idx] + partial[M_ + idx] + partial[2 * M_ + idx] +
                    partial[3 * M_ + idx];
        val[q] = sum;
        lmax = fmaxf(lmax, sum);
    }
    #pragma unroll
    for (int off = 32; off > 0; off >>= 1)
        lmax = fmaxf(lmax, __shfl_down(lmax, off, 64));
    __shared__ float wmax[4];
    if ((tid & 63) == 0) wmax[tid >> 6] = lmax;
    __syncthreads();
    const float gmax = fmaxf(fmaxf(wmax[0], wmax[1]), fmaxf(wmax[2], wmax[3]));
    float lsum = 0.0f;
    #pragma unroll
    for (int q = 0; q < 4; ++q) {
        val[q] = expf(val[q] - gmax);
        lsum += val[q];
    }
    #pragma unroll
    for (int off = 32; off > 0; off >>= 1)
        lsum += __shfl_down(lsum, off, 64);
    __shared__ float wsum[4];
    if ((tid & 63) == 0) wsum[tid >> 6] = lsum;
    __syncthreads();
    const float inv = 1.0f / (wsum[0] + wsum[1] + wsum[2] + wsum[3]);
    #pragma unroll
    for (int q = 0; q < 4; ++q)
        out[b * S_ + tid + 256 * q] = val[q] * inv;
}

// ---------------------------------------------------------------------------
extern "C" void kernel_launch(void* const* d_in, const int* in_sizes, int n_in,
                              void* d_out, int out_size, void* d_ws, size_t ws_size,
                              hipStream_t stream) {
    const float* hidden = (const float*)d_in[0];
    const float* EO     = (const float*)d_in[1];
    const float* W      = (const float*)d_in[2];
    const float* bias   = (const float*)d_in[3];
    const float* v      = (const float*)d_in[4];
    float* out          = (float*)d_out;

    float* hb      = (float*)d_ws;                       // 16384 floats
    float* partial = hb + B_ * H_;                       // 131072 floats
    unsigned short* Wth = (unsigned short*)(partial + 4 * M_);
    unsigned short* Wtl = Wth + (size_t)H_ * K_;

    prep_kernel<<<768, 256, 0, stream>>>(hidden, W, bias, hb, Wth, Wtl);
    gemm_fused<<<dim3(1024), 256, 0, stream>>>(EO, Wth, Wtl, hb, v, partial);
    softmax_kernel<<<B_, 256, 0, stream>>>(partial, out);
}

// Round 3
// 287.728 us; speedup vs baseline: 1.2195x; 1.2195x over previous
//
#include <hip/hip_runtime.h>
#include <math.h>

#define B_ 32
#define S_ 1024
#define H_ 512
#define K_ 1024                 // 2*H
#define M_ (B_ * S_)            // 32768

typedef __attribute__((ext_vector_type(8))) short bf16x8;
typedef __attribute__((ext_vector_type(16))) float f32x16;

// Round-half-up split: f = hi + lo.  Residual r = f - fh is EXACT regardless
// of hi's rounding mode, so half-up matches RNE accuracy (total error =
// lo rounding <= 2^-18 rel).
__device__ __forceinline__ void split_bf16(float f, unsigned short& hi, unsigned short& lo) {
    unsigned u = __float_as_uint(f);
    unsigned r = u + 0x8000u;
    hi = (unsigned short)(r >> 16);
    float fh = __uint_as_float(r & 0xffff0000u);
    float res = f - fh;
    lo = (unsigned short)((__float_as_uint(res) + 0x8000u) >> 16);
}

// split 8 floats -> two 16B LDS stores; v_perm packs 2 halves/op.
__device__ __forceinline__ void split8_store(const float4& x, const float4& y,
                                             unsigned short* hiP, unsigned short* loP) {
    float f[8] = {x.x, x.y, x.z, x.w, y.x, y.y, y.z, y.w};
    unsigned hr[8], lr[8];
    #pragma unroll
    for (int i = 0; i < 8; ++i) {
        unsigned u = __float_as_uint(f[i]);
        unsigned r = u + 0x8000u;
        hr[i] = r;
        float fh = __uint_as_float(r & 0xffff0000u);
        lr[i] = __float_as_uint(f[i] - fh) + 0x8000u;
    }
    uint4 Hv, Lv;
    Hv.x = __builtin_amdgcn_perm(hr[1], hr[0], 0x07060302u);
    Hv.y = __builtin_amdgcn_perm(hr[3], hr[2], 0x07060302u);
    Hv.z = __builtin_amdgcn_perm(hr[5], hr[4], 0x07060302u);
    Hv.w = __builtin_amdgcn_perm(hr[7], hr[6], 0x07060302u);
    Lv.x = __builtin_amdgcn_perm(lr[1], lr[0], 0x07060302u);
    Lv.y = __builtin_amdgcn_perm(lr[3], lr[2], 0x07060302u);
    Lv.z = __builtin_amdgcn_perm(lr[5], lr[4], 0x07060302u);
    Lv.w = __builtin_amdgcn_perm(lr[7], lr[6], 0x07060302u);
    *reinterpret_cast<uint4*>(hiP) = Hv;
    *reinterpret_cast<uint4*>(loP) = Lv;
}

// tanh via HW exp + rcp: (e^2x - 1)/(e^2x + 1).  ~8 ops, |err| ~1e-6.
__device__ __forceinline__ float fast_tanh(float x) {
    float xc = fminf(fmaxf(x, -15.f), 15.f);
    float t = __expf(2.0f * xc);
    return (t - 1.0f) * __builtin_amdgcn_rcpf(t + 1.0f);
}

// async 16B global -> LDS (lane i lands at lds_base + i*16; lds_base wave-uniform)
__device__ __forceinline__ void async_copy16(const void* g, void* l) {
    __builtin_amdgcn_global_load_lds(
        (const __attribute__((address_space(1))) void*)g,
        (__attribute__((address_space(3))) void*)l, 16, 0, 0);
}

// ---------------------------------------------------------------------------
// Kernel 1: merged prep.
//   blocks [0,256):  hb[b][h] = sum_k hidden[b][k]*W[k][h] + bias[h]
//   blocks [256,768): transpose + bf16-split We (K x 512) into FRAGMENT-TILED
//     layout: short index s = ((c*64 + t)*64 + lane)*8 + j  where
//     c = n>>5, t = k>>4, lane = ((k>>3)&1)*32 + (n&31), j = k&7.
//     A wave's B-fragment (32 cols x 16 k) is then ONE coalesced 1KB chunk,
//     DMA-able straight into fragment-linear LDS.
// ---------------------------------------------------------------------------
__global__ __launch_bounds__(256) void prep_kernel(
    const float* __restrict__ hidden, const float* __restrict__ W,
    const float* __restrict__ bias, float* __restrict__ hb,
    unsigned short* __restrict__ Wh, unsigned short* __restrict__ Wl)
{
    __shared__ float red[4][64];
    __shared__ float t[32][33];
    const int bx = blockIdx.x;
    if (bx < 256) {
        const int tid = threadIdx.x;
        const int h0  = (bx & 7) * 64;
        const int b   = bx >> 3;
        const int h   = h0 + (tid & 63);
        const int ks  = tid >> 6;              // 4 k-slices of 128
        const float* hrow = hidden + b * H_;
        float acc = 0.f;
        #pragma unroll 8
        for (int k = ks * 128; k < ks * 128 + 128; ++k)
            acc = fmaf(hrow[k], W[(size_t)k * H_ + h], acc);
        red[ks][tid & 63] = acc;
        __syncthreads();
        if (tid < 64)
            hb[b * H_ + h0 + tid] = red[0][tid] + red[1][tid] + red[2][tid]
                                  + red[3][tid] + bias[h0 + tid];
    } else {
        const float* We = W + (size_t)H_ * H_;   // rows [H, 3H)
        const int cx = bx - 256;                  // 0..511
        const int k0 = (cx & 31) * 32, n0 = (cx >> 5) * 32;
        const int tx = threadIdx.x & 31, ty = threadIdx.x >> 5;   // ty 0..7
        #pragma unroll
        for (int j = 0; j < 4; ++j) {
            const int k = ty + 8 * j;
            t[k][tx] = We[(size_t)(k0 + k) * H_ + n0 + tx];
        }
        __syncthreads();
        #pragma unroll
        for (int j = 0; j < 4; ++j) {
            const int n    = ty + 8 * j;
            const int ncol = n0 + n;
            const int k    = k0 + tx;
            unsigned short hi, lo;
            split_bf16(t[tx][n], hi, lo);
            const int c     = ncol >> 5;
            const int tt    = k >> 4;
            const int lane_ = ((k >> 3) & 1) * 32 + (ncol & 31);
            const size_t s  = ((size_t)(c * 64 + tt) * 64 + lane_) * 8 + (k & 7);
            Wh[s] = hi;
            Wl[s] = lo;
        }
    }
}

// ---------------------------------------------------------------------------
// Kernel 2: 256x256-tile MFMA GEMM (L3-traffic-halving round).
//   Theory: rounds 0-2 all pinned at ~170-200us delivering ~1.07GB of
//   L2-miss traffic (per-XCD working set >> 4MiB L2 -> everything re-served
//   from L3 at ~6TB/s).  256x256 tiles: 32B/out instead of 64B/out -> 537MB.
//   512 threads, 8 waves (2Mx4N, each 128x64), BK=32, double-buffered 128KiB
//   LDS.  A: coalesced fp32->reg->split->ds_write in FRAGMENT order (XOR slot
//   swizzle: reads are a clean 64-slot permutation, writes <=2-way).  B: DMA
//   from pre-tiled global, fragment-linear (zero-conflict base+lane*16 reads).
//   Grid 256 = 1 block/CU; XCD-bijective swizzle pairs the 2 nt-sharers.
// ---------------------------------------------------------------------------
__global__ __launch_bounds__(512, 2) void gemm_fused(
    const float* __restrict__ EO,             // (M, K) fp32
    const unsigned short* __restrict__ Bth,   // tiled (16,64,64,8) bf16 hi
    const unsigned short* __restrict__ Btl,   // tiled (16,64,64,8) bf16 lo
    const float* __restrict__ hb, const float* __restrict__ v,
    float* __restrict__ partial)              // (2, M)
{
    // [buf][hi|lo][ fr(8) x ks(2) x lane(64) x 8 shorts ] = 16KB each
    __shared__ unsigned short ldsA[2][2][8192];
    __shared__ unsigned short ldsB[2][2][8192];

    const int tid  = threadIdx.x;
    // XCD-aware decode: bid%8 = XCD; 32 blocks/XCD = 16 mt x 2 nt, nt fastest.
    const int bid  = blockIdx.x;
    const int jb   = bid >> 3;                    // 0..31
    const int mt   = (bid & 7) * 16 + (jb >> 1);  // 0..127
    const int nt   = jb & 1;                      // 0..1
    const int row0 = mt * 256;
    const int col0 = nt * 256;
    const int batch = row0 >> 10;

    const int lane   = tid & 63;
    const int wave   = tid >> 6;                  // 0..7
    const int wm     = wave >> 2, wn = wave & 3;  // 2M x 4N
    const int lane32 = lane & 31, kh = lane >> 5;

    // ---- A staging geometry: seg = tid + 512*s; m = seg>>2 (0..255); sg = seg&3.
    //      LDS frag-order slot: [fr=m>>5][ks=sg>>1][ (sg&1)*32 + ((m&31)^sg) ][8]
    size_t gA[2];
    int offAw[2];
    #pragma unroll
    for (int s = 0; s < 2; ++s) {
        const int seg = tid + 512 * s;
        const int m = seg >> 2, sg = seg & 3;
        gA[s]    = (size_t)(row0 + m) * K_ + sg * 8;
        offAw[s] = ((m >> 5) * 2 + (sg >> 1)) * 512
                 + ((sg & 1) * 32 + ((m & 31) ^ sg)) * 8;
    }
    // ---- B staging (DMA): wave w stages ci=w; 4 issues (ks x hl).
    //      global frag (c_g = nt*8+w, t = 2i+ks) at shorts c_g*32768 + t*512 + lane*8
    const unsigned short* gBh = Bth + ((size_t)(nt * 8 + wave) * 32768 + lane * 8);
    const unsigned short* gBl = Btl + ((size_t)(nt * 8 + wave) * 32768 + lane * 8);
    const int offBw = wave * 1024;                // + ks*512 per issue (shorts)

    f32x16 acc[4][2];
    #pragma unroll
    for (int fi = 0; fi < 4; ++fi)
        #pragma unroll
        for (int fj = 0; fj < 2; ++fj)
            #pragma unroll
            for (int e = 0; e < 16; ++e)
                acc[fi][fj][e] = 0.f;

    // ---- prologue: stage tile 0 ----
    float4 a0[2], a1[2];
    #pragma unroll
    for (int s = 0; s < 2; ++s) {
        a0[s] = *reinterpret_cast<const float4*>(EO + gA[s]);
        a1[s] = *reinterpret_cast<const float4*>(EO + gA[s] + 4);
    }
    #pragma unroll
    for (int ks = 0; ks < 2; ++ks) {
        async_copy16(gBh + ks * 512, &ldsB[0][0][offBw + ks * 512]);
        async_copy16(gBl + ks * 512, &ldsB[0][1][offBw + ks * 512]);
    }
    #pragma unroll
    for (int s = 0; s < 2; ++s)
        split8_store(a0[s], a1[s], &ldsA[0][0][offAw[s]], &ldsA[0][1][offAw[s]]);

    for (int i = 0; i < 32; ++i) {
        __syncthreads();                      // buf[cur] ready (vmcnt+lgkm drain)
        const int cur = i & 1, nxt = cur ^ 1;
        if (i < 31) {
            const int k0n = 32 * (i + 1);
            #pragma unroll
            for (int s = 0; s < 2; ++s) {
                a0[s] = *reinterpret_cast<const float4*>(EO + gA[s] + k0n);
                a1[s] = *reinterpret_cast<const float4*>(EO + gA[s] + k0n + 4);
            }
            const int tnxt = 2 * (i + 1);
            #pragma unroll
            for (int ks = 0; ks < 2; ++ks) {
                async_copy16(gBh + (tnxt + ks) * 512, &ldsB[nxt][0][offBw + ks * 512]);
                async_copy16(gBl + (tnxt + ks) * 512, &ldsB[nxt][1][offBw + ks * 512]);
            }
        }

        // ---- B fragments (fragment-linear, conflict-free) ----
        bf16x8 b_h[2][2], b_l[2][2];
        #pragma unroll
        for (int fj = 0; fj < 2; ++fj)
            #pragma unroll
            for (int ks = 0; ks < 2; ++ks) {
                const int baseB = ((wn * 2 + fj) * 2 + ks) * 512 + lane * 8;
                b_h[fj][ks] = *reinterpret_cast<const bf16x8*>(&ldsB[cur][0][baseB]);
                b_l[fj][ks] = *reinterpret_cast<const bf16x8*>(&ldsB[cur][1][baseB]);
            }
        // ---- A fragments + MFMA, per fi to bound register pressure ----
        #pragma unroll
        for (int fi = 0; fi < 4; ++fi) {
            bf16x8 a_h[2], a_l[2];
            #pragma unroll
            for (int ks = 0; ks < 2; ++ks) {
                const int baseA = ((wm * 4 + fi) * 2 + ks) * 512
                                + (kh * 32 + (lane32 ^ (2 * ks + kh))) * 8;
                a_h[ks] = *reinterpret_cast<const bf16x8*>(&ldsA[cur][0][baseA]);
                a_l[ks] = *reinterpret_cast<const bf16x8*>(&ldsA[cur][1][baseA]);
            }
            #pragma unroll
            for (int fj = 0; fj < 2; ++fj)
                #pragma unroll
                for (int ks = 0; ks < 2; ++ks) {
                    acc[fi][fj] = __builtin_amdgcn_mfma_f32_32x32x16_bf16(
                        a_h[ks], b_h[fj][ks], acc[fi][fj], 0, 0, 0);
                    acc[fi][fj] = __builtin_amdgcn_mfma_f32_32x32x16_bf16(
                        a_h[ks], b_l[fj][ks], acc[fi][fj], 0, 0, 0);
                    acc[fi][fj] = __builtin_amdgcn_mfma_f32_32x32x16_bf16(
                        a_l[ks], b_h[fj][ks], acc[fi][fj], 0, 0, 0);
                }
        }

        if (i < 31) {                         // split+stage A(i+1) after MFMAs
            #pragma unroll
            for (int s = 0; s < 2; ++s)
                split8_store(a0[s], a1[s],
                             &ldsA[nxt][0][offAw[s]], &ldsA[nxt][1][offAw[s]]);
        }
    }

    // ---- epilogue: tanh(acc + hb)*v, reduce over this block's 256 cols ----
    // Last iter read buf 1; red reuses ldsA[0] (disjoint) -> no hazard.
    // 32x32 C layout: col = lane&31, row = (reg&3) + 8*(reg>>2) + 4*(lane>>5).
    const float* hb_row = hb + batch * H_;
    float hbv[2], vv[2];
    #pragma unroll
    for (int fj = 0; fj < 2; ++fj) {
        const int c = col0 + (wn * 2 + fj) * 32 + lane32;
        hbv[fj] = hb_row[c];
        vv[fj]  = v[c];
    }
    float* red = reinterpret_cast<float*>(&ldsA[0][0][0]);   // 256 rows x 4 wn
    #pragma unroll
    for (int fi = 0; fi < 4; ++fi)
        #pragma unroll
        for (int r = 0; r < 16; ++r) {
            float rs = 0.f;
            #pragma unroll
            for (int fj = 0; fj < 2; ++fj)
                rs = fmaf(fast_tanh(acc[fi][fj][r] + hbv[fj]), vv[fj], rs);
            rs += __shfl_xor(rs, 1, 64);
            rs += __shfl_xor(rs, 2, 64);
            rs += __shfl_xor(rs, 4, 64);
            rs += __shfl_xor(rs, 8, 64);
            rs += __shfl_xor(rs, 16, 64);
            if (lane32 == 0) {
                const int row = wm * 128 + fi * 32 + (r & 3) + 8 * (r >> 2) + 4 * kh;
                red[row * 4 + wn] = rs;
            }
        }
    __syncthreads();
    if (tid < 256)
        partial[(size_t)nt * M_ + row0 + tid] =
            red[tid * 4] + red[tid * 4 + 1] + red[tid * 4 + 2] + red[tid * 4 + 3];
}

// ---------------------------------------------------------------------------
// Kernel 3: per-batch softmax over S=1024 (sum of 2 partials)
// ---------------------------------------------------------------------------
__global__ __launch_bounds__(256) void softmax_kernel(
    const float* __restrict__ partial, float* __restrict__ out)
{
    const int b = blockIdx.x;
    const int tid = threadIdx.x;
    float val[4];
    float lmax = -3.0e38f;
    #pragma unroll
    for (int q = 0; q < 4; ++q) {
        const int idx = b * S_ + tid + 256 * q;
        float sum = partial[idx] + partial[M_ + idx];
        val[q] = sum;
        lmax = fmaxf(lmax, sum);
    }
    #pragma unroll
    for (int off = 32; off > 0; off >>= 1)
        lmax = fmaxf(lmax, __shfl_down(lmax, off, 64));
    __shared__ float wmax[4];
    if ((tid & 63) == 0) wmax[tid >> 6] = lmax;
    __syncthreads();
    const float gmax = fmaxf(fmaxf(wmax[0], wmax[1]), fmaxf(wmax[2], wmax[3]));
    float lsum = 0.0f;
    #pragma unroll
    for (int q = 0; q < 4; ++q) {
        val[q] = expf(val[q] - gmax);
        lsum += val[q];
    }
    #pragma unroll
    for (int off = 32; off > 0; off >>= 1)
        lsum += __shfl_down(lsum, off, 64);
    __shared__ float wsum[4];
    if ((tid & 63) == 0) wsum[tid >> 6] = lsum;
    __syncthreads();
    const float inv = 1.0f / (wsum[0] + wsum[1] + wsum[2] + wsum[3]);
    #pragma unroll
    for (int q = 0; q < 4; ++q)
        out[b * S_ + tid + 256 * q] = val[q] * inv;
}

// ---------------------------------------------------------------------------
extern "C" void kernel_launch(void* const* d_in, const int* in_sizes, int n_in,
                              void* d_out, int out_size, void* d_ws, size_t ws_size,
                              hipStream_t stream) {
    const float* hidden = (const float*)d_in[0];
    const float* EO     = (const float*)d_in[1];
    const float* W      = (const float*)d_in[2];
    const float* bias   = (const float*)d_in[3];
    const float* v      = (const float*)d_in[4];
    float* out          = (float*)d_out;

    float* hb      = (float*)d_ws;                       // 16384 floats
    float* partial = hb + B_ * H_;                       // 2*M floats used
    unsigned short* Wth = (unsigned short*)(partial + 4 * M_);
    unsigned short* Wtl = Wth + (size_t)H_ * K_;

    prep_kernel<<<768, 256, 0, stream>>>(hidden, W, bias, hb, Wth, Wtl);
    gemm_fused<<<dim3(256), 512, 0, stream>>>(EO, Wth, Wtl, hb, v, partial);
    softmax_kernel<<<B_, 256, 0, stream>>>(partial, out);
}

// Round 4
// 287.057 us; speedup vs baseline: 1.2224x; 1.0023x over previous
//
#include <hip/hip_runtime.h>
#include <math.h>

#define B_ 32
#define S_ 1024
#define H_ 512
#define K_ 1024                 // 2*H
#define M_ (B_ * S_)            // 32768

typedef __attribute__((ext_vector_type(8))) short bf16x8;
typedef __attribute__((ext_vector_type(16))) float f32x16;

// Round-half-up split: f = hi + lo.  Residual r = f - fh is EXACT regardless
// of hi's rounding mode, so half-up matches RNE accuracy (total error =
// lo rounding <= 2^-18 rel).
__device__ __forceinline__ void split_bf16(float f, unsigned short& hi, unsigned short& lo) {
    unsigned u = __float_as_uint(f);
    unsigned r = u + 0x8000u;
    hi = (unsigned short)(r >> 16);
    float fh = __uint_as_float(r & 0xffff0000u);
    float res = f - fh;
    lo = (unsigned short)((__float_as_uint(res) + 0x8000u) >> 16);
}

// split 8 floats -> two 16B LDS stores; v_perm packs 2 halves/op.
__device__ __forceinline__ void split8_store(const float4& x, const float4& y,
                                             unsigned short* hiP, unsigned short* loP) {
    float f[8] = {x.x, x.y, x.z, x.w, y.x, y.y, y.z, y.w};
    unsigned hr[8], lr[8];
    #pragma unroll
    for (int i = 0; i < 8; ++i) {
        unsigned u = __float_as_uint(f[i]);
        unsigned r = u + 0x8000u;
        hr[i] = r;
        float fh = __uint_as_float(r & 0xffff0000u);
        lr[i] = __float_as_uint(f[i] - fh) + 0x8000u;
    }
    uint4 Hv, Lv;
    Hv.x = __builtin_amdgcn_perm(hr[1], hr[0], 0x07060302u);
    Hv.y = __builtin_amdgcn_perm(hr[3], hr[2], 0x07060302u);
    Hv.z = __builtin_amdgcn_perm(hr[5], hr[4], 0x07060302u);
    Hv.w = __builtin_amdgcn_perm(hr[7], hr[6], 0x07060302u);
    Lv.x = __builtin_amdgcn_perm(lr[1], lr[0], 0x07060302u);
    Lv.y = __builtin_amdgcn_perm(lr[3], lr[2], 0x07060302u);
    Lv.z = __builtin_amdgcn_perm(lr[5], lr[4], 0x07060302u);
    Lv.w = __builtin_amdgcn_perm(lr[7], lr[6], 0x07060302u);
    *reinterpret_cast<uint4*>(hiP) = Hv;
    *reinterpret_cast<uint4*>(loP) = Lv;
}

// tanh via HW exp + rcp: (e^2x - 1)/(e^2x + 1).  ~8 ops, |err| ~1e-6.
__device__ __forceinline__ float fast_tanh(float x) {
    float xc = fminf(fmaxf(x, -15.f), 15.f);
    float t = __expf(2.0f * xc);
    return (t - 1.0f) * __builtin_amdgcn_rcpf(t + 1.0f);
}

// async 16B global -> LDS (lane i lands at lds_base + i*16; lds_base wave-uniform)
__device__ __forceinline__ void async_copy16(const void* g, void* l) {
    __builtin_amdgcn_global_load_lds(
        (const __attribute__((address_space(1))) void*)g,
        (__attribute__((address_space(3))) void*)l, 16, 0, 0);
}

// ---------------------------------------------------------------------------
// Kernel 1: merged prep.
//   blocks [0,256):  hb[b][h] = sum_k hidden[b][k]*W[k][h] + bias[h]
//   blocks [256,768): transpose + bf16-split We (K x 512) into FRAGMENT-TILED
//     layout: short index s = ((c*64 + t)*64 + lane)*8 + j  where
//     c = n>>5, t = k>>4, lane = ((k>>3)&1)*32 + (n&31), j = k&7.
// ---------------------------------------------------------------------------
__global__ __launch_bounds__(256) void prep_kernel(
    const float* __restrict__ hidden, const float* __restrict__ W,
    const float* __restrict__ bias, float* __restrict__ hb,
    unsigned short* __restrict__ Wh, unsigned short* __restrict__ Wl)
{
    __shared__ float red[4][64];
    __shared__ float t[32][33];
    const int bx = blockIdx.x;
    if (bx < 256) {
        const int tid = threadIdx.x;
        const int h0  = (bx & 7) * 64;
        const int b   = bx >> 3;
        const int h   = h0 + (tid & 63);
        const int ks  = tid >> 6;              // 4 k-slices of 128
        const float* hrow = hidden + b * H_;
        float acc = 0.f;
        #pragma unroll 8
        for (int k = ks * 128; k < ks * 128 + 128; ++k)
            acc = fmaf(hrow[k], W[(size_t)k * H_ + h], acc);
        red[ks][tid & 63] = acc;
        __syncthreads();
        if (tid < 64)
            hb[b * H_ + h0 + tid] = red[0][tid] + red[1][tid] + red[2][tid]
                                  + red[3][tid] + bias[h0 + tid];
    } else {
        const float* We = W + (size_t)H_ * H_;   // rows [H, 3H)
        const int cx = bx - 256;                  // 0..511
        const int k0 = (cx & 31) * 32, n0 = (cx >> 5) * 32;
        const int tx = threadIdx.x & 31, ty = threadIdx.x >> 5;   // ty 0..7
        #pragma unroll
        for (int j = 0; j < 4; ++j) {
            const int k = ty + 8 * j;
            t[k][tx] = We[(size_t)(k0 + k) * H_ + n0 + tx];
        }
        __syncthreads();
        #pragma unroll
        for (int j = 0; j < 4; ++j) {
            const int n    = ty + 8 * j;
            const int ncol = n0 + n;
            const int k    = k0 + tx;
            unsigned short hi, lo;
            split_bf16(t[tx][n], hi, lo);
            const int c     = ncol >> 5;
            const int tt    = k >> 4;
            const int lane_ = ((k >> 3) & 1) * 32 + (ncol & 31);
            const size_t s  = ((size_t)(c * 64 + tt) * 64 + lane_) * 8 + (k & 7);
            Wh[s] = hi;
            Wl[s] = lo;
        }
    }
}

// ---------------------------------------------------------------------------
// Kernel 2: 256x256 MFMA GEMM with COUNTED-vmcnt soft barriers (T4) + T5.
//   Round-3 post-mortem: per-step cost ~11300cy vs ~768cy MFMA — the
//   __syncthreads vmcnt(0)+lgkm(0) drain of the same-step B-DMA, with 1
//   block/CU (no TLP partner), was ~85% of the time.  This round:
//   - B triple-buffered (3x32KB): DMA for step j+2 issued at step j,
//     waited only at end of step j+1 (full-step latency cover).
//   - barriers are fused asm "s_waitcnt vmcnt(4) lgkmcnt(0); s_barrier":
//     the 4 newest B-DMAs stay in flight ACROSS the barrier, never drain
//     to 0 in the loop.  Correctness is count-based: each step's 8 VMEM
//     ops sit between memory-clobber asms, so <=4-outstanding implies
//     everything older (incl. B(j+1)) retired, independent of intra-step
//     compiler reordering.
//   - s_setprio(1) around the ds_read+MFMA cluster (T5; waves now occupy
//     different roles between soft barriers).
//   A stays depth-1 reg-staged (load at step top, split after MFMAs).
//   LDS = 64KB (A dbuf) + 96KB (B tbuf) = 160KiB (full pool, 1 block/CU).
// ---------------------------------------------------------------------------
__global__ __launch_bounds__(512, 2) void gemm_fused(
    const float* __restrict__ EO,             // (M, K) fp32
    const unsigned short* __restrict__ Bth,   // tiled (16,64,64,8) bf16 hi
    const unsigned short* __restrict__ Btl,   // tiled (16,64,64,8) bf16 lo
    const float* __restrict__ hb, const float* __restrict__ v,
    float* __restrict__ partial)              // (2, M)
{
    __shared__ unsigned short ldsA[2][2][8192];   // 64KB  [buf][hi|lo]
    __shared__ unsigned short ldsB[3][2][8192];   // 96KB  [buf][hi|lo]

    const int tid  = threadIdx.x;
    // XCD-aware decode: bid%8 = XCD; 32 blocks/XCD = 16 mt x 2 nt, nt fastest.
    const int bid  = blockIdx.x;
    const int jb   = bid >> 3;                    // 0..31
    const int mt   = (bid & 7) * 16 + (jb >> 1);  // 0..127
    const int nt   = jb & 1;                      // 0..1
    const int row0 = mt * 256;
    const int col0 = nt * 256;
    const int batch = row0 >> 10;

    const int lane   = tid & 63;
    const int wave   = tid >> 6;                  // 0..7
    const int wm     = wave >> 2, wn = wave & 3;  // 2M x 4N
    const int lane32 = lane & 31, kh = lane >> 5;

    // ---- A staging geometry: seg = tid + 512*s; m = seg>>2 (0..255); sg = seg&3.
    size_t gA[2];
    int offAw[2];
    #pragma unroll
    for (int s = 0; s < 2; ++s) {
        const int seg = tid + 512 * s;
        const int m = seg >> 2, sg = seg & 3;
        gA[s]    = (size_t)(row0 + m) * K_ + sg * 8;
        offAw[s] = ((m >> 5) * 2 + (sg >> 1)) * 512
                 + ((sg & 1) * 32 + ((m & 31) ^ sg)) * 8;
    }
    // ---- B staging (DMA): wave w stages frag slots {2w, 2w+1}.
    const unsigned short* gBh = Bth + ((size_t)(nt * 8 + wave) * 32768 + lane * 8);
    const unsigned short* gBl = Btl + ((size_t)(nt * 8 + wave) * 32768 + lane * 8);
    const int offBw = wave * 1024;                // shorts; + ks*512 per issue

    f32x16 acc[4][2];
    #pragma unroll
    for (int fi = 0; fi < 4; ++fi)
        #pragma unroll
        for (int fj = 0; fj < 2; ++fj)
            #pragma unroll
            for (int e = 0; e < 16; ++e)
                acc[fi][fj][e] = 0.f;

    // ---- prologue ----
    float4 a0[2], a1[2];
    #pragma unroll
    for (int s = 0; s < 2; ++s) {                 // A(0) -> regs
        a0[s] = *reinterpret_cast<const float4*>(EO + gA[s]);
        a1[s] = *reinterpret_cast<const float4*>(EO + gA[s] + 4);
    }
    #pragma unroll
    for (int s = 0; s < 2; ++s)                   // split -> ldsA[0]
        split8_store(a0[s], a1[s], &ldsA[0][0][offAw[s]], &ldsA[0][1][offAw[s]]);
    #pragma unroll
    for (int ks = 0; ks < 2; ++ks) {              // DMA B(0) -> ldsB[0]
        async_copy16(gBh + (0 + ks) * 512, &ldsB[0][0][offBw + ks * 512]);
        async_copy16(gBl + (0 + ks) * 512, &ldsB[0][1][offBw + ks * 512]);
    }
    #pragma unroll
    for (int ks = 0; ks < 2; ++ks) {              // DMA B(1) -> ldsB[1]
        async_copy16(gBh + (2 + ks) * 512, &ldsB[1][0][offBw + ks * 512]);
        async_copy16(gBl + (2 + ks) * 512, &ldsB[1][1][offBw + ks * 512]);
    }
    // B(0) retired (4 oldest of 8); B(1) stays in flight across the barrier.
    asm volatile("s_waitcnt vmcnt(4) lgkmcnt(0)\n\ts_barrier" ::: "memory");

    int bc = 0;                                   // = j % 3
    for (int j = 0; j < 32; ++j) {
        const int cur = j & 1, nxt = cur ^ 1;
        const int bn  = (bc >= 1) ? bc - 1 : 2;   // (j+2) % 3

        if (j < 31) {                             // A(j+1) -> regs
            const int k0n = 32 * (j + 1);
            #pragma unroll
            for (int s = 0; s < 2; ++s) {
                a0[s] = *reinterpret_cast<const float4*>(EO + gA[s] + k0n);
                a1[s] = *reinterpret_cast<const float4*>(EO + gA[s] + k0n + 4);
            }
        }
        if (j < 30) {                             // DMA B(j+2) -> ldsB[bn]
            const int tnxt = 2 * (j + 2);
            #pragma unroll
            for (int ks = 0; ks < 2; ++ks) {
                async_copy16(gBh + (tnxt + ks) * 512, &ldsB[bn][0][offBw + ks * 512]);
                async_copy16(gBl + (tnxt + ks) * 512, &ldsB[bn][1][offBw + ks * 512]);
            }
        }

        __builtin_amdgcn_s_setprio(1);
        // ---- B fragments (fragment-linear, conflict-free) ----
        bf16x8 b_h[2][2], b_l[2][2];
        #pragma unroll
        for (int fj = 0; fj < 2; ++fj)
            #pragma unroll
            for (int ks = 0; ks < 2; ++ks) {
                const int baseB = ((wn * 2 + fj) * 2 + ks) * 512 + lane * 8;
                b_h[fj][ks] = *reinterpret_cast<const bf16x8*>(&ldsB[bc][0][baseB]);
                b_l[fj][ks] = *reinterpret_cast<const bf16x8*>(&ldsB[bc][1][baseB]);
            }
        // ---- A fragments + MFMA, per fi to bound register pressure ----
        #pragma unroll
        for (int fi = 0; fi < 4; ++fi) {
            bf16x8 a_h[2], a_l[2];
            #pragma unroll
            for (int ks = 0; ks < 2; ++ks) {
                const int baseA = ((wm * 4 + fi) * 2 + ks) * 512
                                + (kh * 32 + (lane32 ^ (2 * ks + kh))) * 8;
                a_h[ks] = *reinterpret_cast<const bf16x8*>(&ldsA[cur][0][baseA]);
                a_l[ks] = *reinterpret_cast<const bf16x8*>(&ldsA[cur][1][baseA]);
            }
            #pragma unroll
            for (int fj = 0; fj < 2; ++fj)
                #pragma unroll
                for (int ks = 0; ks < 2; ++ks) {
                    acc[fi][fj] = __builtin_amdgcn_mfma_f32_32x32x16_bf16(
                        a_h[ks], b_h[fj][ks], acc[fi][fj], 0, 0, 0);
                    acc[fi][fj] = __builtin_amdgcn_mfma_f32_32x32x16_bf16(
                        a_h[ks], b_l[fj][ks], acc[fi][fj], 0, 0, 0);
                    acc[fi][fj] = __builtin_amdgcn_mfma_f32_32x32x16_bf16(
                        a_l[ks], b_h[fj][ks], acc[fi][fj], 0, 0, 0);
                }
        }
        __builtin_amdgcn_s_setprio(0);

        if (j < 30) {
            // split A(j+1) (compiler auto-waits its loads) -> ldsA[nxt]
            #pragma unroll
            for (int s = 0; s < 2; ++s)
                split8_store(a0[s], a1[s],
                             &ldsA[nxt][0][offAw[s]], &ldsA[nxt][1][offAw[s]]);
            // keep the 4 newest (B(j+2) DMAs) in flight across the barrier
            asm volatile("s_waitcnt vmcnt(4) lgkmcnt(0)\n\ts_barrier" ::: "memory");
        } else if (j == 30) {
            #pragma unroll
            for (int s = 0; s < 2; ++s)
                split8_store(a0[s], a1[s],
                             &ldsA[nxt][0][offAw[s]], &ldsA[nxt][1][offAw[s]]);
            // nothing issued this step: drain (B(31) must be readable next)
            asm volatile("s_waitcnt vmcnt(0) lgkmcnt(0)\n\ts_barrier" ::: "memory");
        }
        bc = (bc == 2) ? 0 : bc + 1;
    }

    // ---- epilogue: tanh(acc + hb)*v, reduce over this block's 256 cols ----
    // Step 31 read ldsA[1]/ldsB[1]; red reuses ldsA[0] (disjoint).
    // 32x32 C layout: col = lane&31, row = (reg&3) + 8*(reg>>2) + 4*(lane>>5).
    const float* hb_row = hb + batch * H_;
    float hbv[2], vv[2];
    #pragma unroll
    for (int fj = 0; fj < 2; ++fj) {
        const int c = col0 + (wn * 2 + fj) * 32 + lane32;
        hbv[fj] = hb_row[c];
        vv[fj]  = v[c];
    }
    float* red = reinterpret_cast<float*>(&ldsA[0][0][0]);   // 256 rows x 4 wn
    #pragma unroll
    for (int fi = 0; fi < 4; ++fi)
        #pragma unroll
        for (int r = 0; r < 16; ++r) {
            float rs = 0.f;
            #pragma unroll
            for (int fj = 0; fj < 2; ++fj)
                rs = fmaf(fast_tanh(acc[fi][fj][r] + hbv[fj]), vv[fj], rs);
            rs += __shfl_xor(rs, 1, 64);
            rs += __shfl_xor(rs, 2, 64);
            rs += __shfl_xor(rs, 4, 64);
            rs += __shfl_xor(rs, 8, 64);
            rs += __shfl_xor(rs, 16, 64);
            if (lane32 == 0) {
                const int row = wm * 128 + fi * 32 + (r & 3) + 8 * (r >> 2) + 4 * kh;
                red[row * 4 + wn] = rs;
            }
        }
    __syncthreads();
    if (tid < 256)
        partial[(size_t)nt * M_ + row0 + tid] =
            red[tid * 4] + red[tid * 4 + 1] + red[tid * 4 + 2] + red[tid * 4 + 3];
}

// ---------------------------------------------------------------------------
// Kernel 3: per-batch softmax over S=1024 (sum of 2 partials)
// ---------------------------------------------------------------------------
__global__ __launch_bounds__(256) void softmax_kernel(
    const float* __restrict__ partial, float* __restrict__ out)
{
    const int b = blockIdx.x;
    const int tid = threadIdx.x;
    float val[4];
    float lmax = -3.0e38f;
    #pragma unroll
    for (int q = 0; q < 4; ++q) {
        const int idx = b * S_ + tid + 256 * q;
        float sum = partial[idx] + partial[M_ + idx];
        val[q] = sum;
        lmax = fmaxf(lmax, sum);
    }
    #pragma unroll
    for (int off = 32; off > 0; off >>= 1)
        lmax = fmaxf(lmax, __shfl_down(lmax, off, 64));
    __shared__ float wmax[4];
    if ((tid & 63) == 0) wmax[tid >> 6] = lmax;
    __syncthreads();
    const float gmax = fmaxf(fmaxf(wmax[0], wmax[1]), fmaxf(wmax[2], wmax[3]));
    float lsum = 0.0f;
    #pragma unroll
    for (int q = 0; q < 4; ++q) {
        val[q] = expf(val[q] - gmax);
        lsum += val[q];
    }
    #pragma unroll
    for (int off = 32; off > 0; off >>= 1)
        lsum += __shfl_down(lsum, off, 64);
    __shared__ float wsum[4];
    if ((tid & 63) == 0) wsum[tid >> 6] = lsum;
    __syncthreads();
    const float inv = 1.0f / (wsum[0] + wsum[1] + wsum[2] + wsum[3]);
    #pragma unroll
    for (int q = 0; q < 4; ++q)
        out[b * S_ + tid + 256 * q] = val[q] * inv;
}

// ---------------------------------------------------------------------------
extern "C" void kernel_launch(void* const* d_in, const int* in_sizes, int n_in,
                              void* d_out, int out_size, void* d_ws, size_t ws_size,
                              hipStream_t stream) {
    const float* hidden = (const float*)d_in[0];
    const float* EO     = (const float*)d_in[1];
    const float* W      = (const float*)d_in[2];
    const float* bias   = (const float*)d_in[3];
    const float* v      = (const float*)d_in[4];
    float* out          = (float*)d_out;

    float* hb      = (float*)d_ws;                       // 16384 floats
    float* partial = hb + B_ * H_;                       // 2*M floats used
    unsigned short* Wth = (unsigned short*)(partial + 4 * M_);
    unsigned short* Wtl = Wth + (size_t)H_ * K_;

    prep_kernel<<<768, 256, 0, stream>>>(hidden, W, bias, hb, Wth, Wtl);
    gemm_fused<<<dim3(256), 512, 0, stream>>>(EO, Wth, Wtl, hb, v, partial);
    softmax_kernel<<<B_, 256, 0, stream>>>(partial, out);
}